// Round 5
// baseline (820.138 us; speedup 1.0000x reference)
//
#include <hip/hip_runtime.h>
#include <stdint.h>

#define DIM 256
#define NEG_SLOPE 0.01f

typedef float    vfloat4 __attribute__((ext_vector_type(4)));
typedef _Float16 vhalf4  __attribute__((ext_vector_type(4)));
typedef unsigned int vuint2 __attribute__((ext_vector_type(2)));

// ---------------- utility kernels ----------------

__global__ __launch_bounds__(256) void zero_i32_kernel(int* __restrict__ p, int n) {
    int i = blockIdx.x * blockDim.x + threadIdx.x;
    int stride = gridDim.x * blockDim.x;
    for (; i < n; i += stride) p[i] = 0;
}

__global__ __launch_bounds__(256) void zero_f32_kernel(float* __restrict__ p, long long n) {
    long long i = (long long)blockIdx.x * blockDim.x + threadIdx.x;
    long long stride = (long long)gridDim.x * blockDim.x;
    for (; i < n; i += stride) p[i] = 0.0f;
}

// ---------------- GEMM: h = x @ W^T + b  (fp32 math, fp16 output) ----------------

#define GBM 128
#define GBN 64
#define GBK 16
#define GLDA 132
#define GLDB 68

__global__ __launch_bounds__(256) void gemm_xwT_kernel(
        const float* __restrict__ x, const float* __restrict__ W,
        const float* __restrict__ bias, _Float16* __restrict__ h, int M) {
    __shared__ float As[GBK][GLDA];
    __shared__ float Bs[GBK][GLDB];

    const int tid  = threadIdx.x;
    const int row0 = blockIdx.x * GBM;
    const int col0 = blockIdx.y * GBN;
    const int ty = tid >> 4;
    const int tx = tid & 15;
    const int lr = tid >> 2;
    const int lk = (tid & 3) * 4;

    float acc[8][4];
#pragma unroll
    for (int i = 0; i < 8; ++i)
#pragma unroll
        for (int j = 0; j < 4; ++j) acc[i][j] = 0.0f;

    for (int kk = 0; kk < DIM; kk += GBK) {
#pragma unroll
        for (int i = 0; i < 2; ++i) {
            int row = row0 + lr + i * 64;
            vfloat4 av = {0.f, 0.f, 0.f, 0.f};
            if (row < M)
                av = __builtin_nontemporal_load((const vfloat4*)(&x[(size_t)row * DIM + kk + lk]));
            As[lk + 0][lr + i * 64] = av.x; As[lk + 1][lr + i * 64] = av.y;
            As[lk + 2][lr + i * 64] = av.z; As[lk + 3][lr + i * 64] = av.w;
        }
        float4 bv = *(const float4*)(&W[(size_t)(col0 + lr) * DIM + kk + lk]);
        Bs[lk + 0][lr] = bv.x; Bs[lk + 1][lr] = bv.y;
        Bs[lk + 2][lr] = bv.z; Bs[lk + 3][lr] = bv.w;
        __syncthreads();

#pragma unroll
        for (int k = 0; k < GBK; ++k) {
            float4 a0 = *(const float4*)(&As[k][ty * 8]);
            float4 a1 = *(const float4*)(&As[k][ty * 8 + 4]);
            float4 b  = *(const float4*)(&Bs[k][tx * 4]);
            float ar[8] = {a0.x, a0.y, a0.z, a0.w, a1.x, a1.y, a1.z, a1.w};
            float br[4] = {b.x, b.y, b.z, b.w};
#pragma unroll
            for (int i = 0; i < 8; ++i)
#pragma unroll
                for (int j = 0; j < 4; ++j)
                    acc[i][j] += ar[i] * br[j];
        }
        __syncthreads();
    }

    const float4 bvec = *(const float4*)(&bias[col0 + tx * 4]);
#pragma unroll
    for (int i = 0; i < 8; ++i) {
        int row = row0 + ty * 8 + i;
        if (row < M) {
            vhalf4 o;
            o.x = (_Float16)(acc[i][0] + bvec.x);
            o.y = (_Float16)(acc[i][1] + bvec.y);
            o.z = (_Float16)(acc[i][2] + bvec.z);
            o.w = (_Float16)(acc[i][3] + bvec.w);
            *(vhalf4*)(&h[(size_t)row * DIM + col0 + tx * 4]) = o;
        }
    }
}

// ---------------- CSR build ----------------

__global__ __launch_bounds__(256) void hist_kernel(const int* __restrict__ rows,
                                                   int* __restrict__ cnt, int E) {
    int i = blockIdx.x * blockDim.x + threadIdx.x;
    int stride = gridDim.x * blockDim.x;
    for (; i < E; i += stride)
        atomicAdd(&cnt[__builtin_nontemporal_load(&rows[i])], 1);
}

__device__ inline int wave_incl_scan(int v) {
    const int lane = threadIdx.x & 63;
#pragma unroll
    for (int off = 1; off < 64; off <<= 1) {
        int t = __shfl_up(v, off, 64);
        if (lane >= off) v += t;
    }
    return v;
}

#define SCHUNK 2048   // 256 threads x 8 elements

__global__ __launch_bounds__(256) void chunk_sum_kernel(const int* __restrict__ cnt,
                                                        int* __restrict__ psum, int n) {
    __shared__ int wtot[4];
    const int tid = (int)threadIdx.x;
    const int lane = tid & 63, wid = tid >> 6;
    const int base = blockIdx.x * SCHUNK + tid * 8;
    int s = 0;
#pragma unroll
    for (int i = 0; i < 8; ++i) {
        int idx = base + i;
        if (idx < n) s += cnt[idx];
    }
#pragma unroll
    for (int off = 32; off; off >>= 1) s += __shfl_xor(s, off, 64);
    if (lane == 0) wtot[wid] = s;
    __syncthreads();
    if (tid == 0) psum[blockIdx.x] = wtot[0] + wtot[1] + wtot[2] + wtot[3];
}

__global__ __launch_bounds__(64) void scan_psum_kernel(int* __restrict__ psum, int nchunks) {
    const int lane = (int)threadIdx.x;
    int run = 0;
    for (int b = 0; b < nchunks; b += 64) {
        int i = b + lane;
        int v = (i < nchunks) ? psum[i] : 0;
        int incl = wave_incl_scan(v);
        if (i < nchunks) psum[i] = run + incl - v;
        run += __shfl(incl, 63, 64);
    }
}

__global__ __launch_bounds__(256) void scan_final_kernel(const int* __restrict__ cnt,
        const int* __restrict__ psum, int* __restrict__ offs,
        int* __restrict__ cursor, int n) {
    __shared__ int wtot[4];
    const int tid = (int)threadIdx.x;
    const int lane = tid & 63, wid = tid >> 6;
    const int base = blockIdx.x * SCHUNK + tid * 8;
    int v[8];
    int ts = 0;
#pragma unroll
    for (int i = 0; i < 8; ++i) {
        int idx = base + i;
        v[i] = (idx < n) ? cnt[idx] : 0;
        ts += v[i];
    }
    int incl = wave_incl_scan(ts);
    if (lane == 63) wtot[wid] = incl;
    __syncthreads();
    int woff = 0;
    for (int w = 0; w < wid; ++w) woff += wtot[w];
    int run = psum[blockIdx.x] + woff + incl - ts;
#pragma unroll
    for (int i = 0; i < 8; ++i) {
        int idx = base + i;
        if (idx < n) { offs[idx] = run; cursor[idx] = run; }
        run += v[i];
    }
}

// scatter: NT loads keep L2 free for the destination lines -> write merging.
__global__ __launch_bounds__(256) void scatter_kernel(
        const int* __restrict__ rows, const int* __restrict__ cols,
        const float* __restrict__ vals, int* __restrict__ cursor,
        vuint2* __restrict__ sorted, int E) {
    int i = blockIdx.x * blockDim.x + threadIdx.x;
    int stride = gridDim.x * blockDim.x;
    for (; i < E; i += stride) {
        int r = __builtin_nontemporal_load(&rows[i]);
        int c = __builtin_nontemporal_load(&cols[i]);
        float v = __builtin_nontemporal_load(&vals[i]);
        int pos = atomicAdd(&cursor[r], 1);
        vuint2 rec;
        rec.x = (unsigned)c;
        rec.y = __float_as_uint(v);
        sorted[pos] = rec;
    }
}

// ---------------- aggregation: one wave per node, 4 nodes/block ----------------

__global__ __launch_bounds__(256) void agg_kernel(
        const _Float16* __restrict__ h, const vuint2* __restrict__ sorted,
        const int* __restrict__ offs, const int* __restrict__ cnt,
        float* __restrict__ out, int N) {
    const int node = blockIdx.x * 4 + ((int)threadIdx.x >> 6);
    if (node >= N) return;
    const int lane = (int)threadIdx.x & 63;
    const int beg = offs[node];
    const int end = beg + cnt[node];

    float4 acc0 = make_float4(0.f, 0.f, 0.f, 0.f);
    float4 acc1 = make_float4(0.f, 0.f, 0.f, 0.f);

    int j = beg;
    for (; j + 7 < end; j += 8) {
        vuint2 cv[8];
        vhalf4 hv[8];
#pragma unroll
        for (int u = 0; u < 8; ++u) cv[u] = __builtin_nontemporal_load(&sorted[j + u]);
#pragma unroll
        for (int u = 0; u < 8; ++u)
            hv[u] = *(const vhalf4*)(&h[(size_t)cv[u].x * DIM + lane * 4]);
#pragma unroll
        for (int u = 0; u < 8; ++u) {
            float v = __uint_as_float(cv[u].y);
            float4* a = (u & 1) ? &acc1 : &acc0;
            a->x += v * (float)hv[u].x;
            a->y += v * (float)hv[u].y;
            a->z += v * (float)hv[u].z;
            a->w += v * (float)hv[u].w;
        }
    }
    for (; j < end; ++j) {
        vuint2 cv = __builtin_nontemporal_load(&sorted[j]);
        float v = __uint_as_float(cv.y);
        vhalf4 hv = *(const vhalf4*)(&h[(size_t)cv.x * DIM + lane * 4]);
        acc0.x += v * (float)hv.x; acc0.y += v * (float)hv.y;
        acc0.z += v * (float)hv.z; acc0.w += v * (float)hv.w;
    }
    vfloat4 a;
    a.x = acc0.x + acc1.x;
    a.y = acc0.y + acc1.y;
    a.z = acc0.z + acc1.z;
    a.w = acc0.w + acc1.w;
    a.x = (a.x >= 0.f) ? a.x : NEG_SLOPE * a.x;
    a.y = (a.y >= 0.f) ? a.y : NEG_SLOPE * a.y;
    a.z = (a.z >= 0.f) ? a.z : NEG_SLOPE * a.z;
    a.w = (a.w >= 0.f) ? a.w : NEG_SLOPE * a.w;
    __builtin_nontemporal_store(a, (vfloat4*)(&out[(size_t)node * DIM + lane * 4]));
}

// ---------------- fallback: atomic scatter (only if ws too small for CSR) ----------------

__global__ __launch_bounds__(64) void edge_atomic_kernel(
        const int* __restrict__ rows, const int* __restrict__ cols,
        const float* __restrict__ vals, const _Float16* __restrict__ h,
        float* __restrict__ out, int E) {
    const int e = blockIdx.x;
    if (e >= E) return;
    const int lane = threadIdx.x;
    const int r = rows[e];
    const int c = cols[e];
    const float v = vals[e];
    vhalf4 hv = *(const vhalf4*)(&h[(size_t)c * DIM + lane * 4]);
    float* dst = &out[(size_t)r * DIM + lane * 4];
    atomicAdd(dst + 0, v * (float)hv.x);
    atomicAdd(dst + 1, v * (float)hv.y);
    atomicAdd(dst + 2, v * (float)hv.z);
    atomicAdd(dst + 3, v * (float)hv.w);
}

__global__ __launch_bounds__(256) void leaky_kernel(float* __restrict__ p, long long n) {
    long long i = (long long)blockIdx.x * blockDim.x + threadIdx.x;
    long long stride = (long long)gridDim.x * blockDim.x;
    for (; i < n; i += stride) {
        float v = p[i];
        p[i] = (v >= 0.f) ? v : NEG_SLOPE * v;
    }
}

// ---------------- launch ----------------

extern "C" void kernel_launch(void* const* d_in, const int* in_sizes, int n_in,
                              void* d_out, int out_size, void* d_ws, size_t ws_size,
                              hipStream_t stream) {
    const float* x    = (const float*)d_in[0];
    const int*   erow = (const int*)d_in[1];
    const int*   ecol = (const int*)d_in[2];
    const float* eval_ = (const float*)d_in[3];
    const float* Ww   = (const float*)d_in[4];
    const float* Wb   = (const float*)d_in[5];
    float* out = (float*)d_out;

    const int N = in_sizes[0] / DIM;
    const int E = in_sizes[1];
    const int nchunks = (N + SCHUNK - 1) / SCHUNK;

    // workspace layout
    char* p = (char*)d_ws;
    _Float16* h = (_Float16*)p;                 p += (size_t)N * DIM * sizeof(_Float16);
    int* cnt = (int*)p;                         p += (size_t)N * sizeof(int);
    int* offs = (int*)p;                        p += (size_t)N * sizeof(int);
    int* cursor = (int*)p;                      p += (size_t)N * sizeof(int);
    int* psum = (int*)p;                        p += (size_t)((nchunks + 63) & ~63) * sizeof(int);
    uintptr_t up = ((uintptr_t)p + 15) & ~(uintptr_t)15;
    vuint2* sorted = (vuint2*)up;
    size_t need_full = (size_t)((char*)sorted - (char*)d_ws) + (size_t)E * sizeof(vuint2);
    size_t need_h = (size_t)N * DIM * sizeof(_Float16);

    dim3 ggrid((N + GBM - 1) / GBM, DIM / GBN);

    if (ws_size >= need_full) {
        // Phase 1: CSR build (before GEMM so h is L2-hot right before agg)
        zero_i32_kernel<<<256, 256, 0, stream>>>(cnt, N);
        hist_kernel<<<1024, 256, 0, stream>>>(erow, cnt, E);
        chunk_sum_kernel<<<nchunks, 256, 0, stream>>>(cnt, psum, N);
        scan_psum_kernel<<<1, 64, 0, stream>>>(psum, nchunks);
        scan_final_kernel<<<nchunks, 256, 0, stream>>>(cnt, psum, offs, cursor, N);
        scatter_kernel<<<2048, 256, 0, stream>>>(erow, ecol, eval_, cursor, sorted, E);
        // Phase 2: h = x @ W^T + b  (fp16 out)
        gemm_xwT_kernel<<<ggrid, 256, 0, stream>>>(x, Ww, Wb, h, N);
        // Phase 3: per-node aggregation + fused leaky-relu
        agg_kernel<<<(N + 3) / 4, 256, 0, stream>>>(h, sorted, offs, cnt, out, N);
    } else if (ws_size >= need_h) {
        gemm_xwT_kernel<<<ggrid, 256, 0, stream>>>(x, Ww, Wb, h, N);
        zero_f32_kernel<<<2048, 256, 0, stream>>>(out, (long long)N * DIM);
        edge_atomic_kernel<<<E, 64, 0, stream>>>(erow, ecol, eval_, h, out, E);
        leaky_kernel<<<2048, 256, 0, stream>>>(out, (long long)N * DIM);
    }
}

// Round 6
// 792.626 us; speedup vs baseline: 1.0347x; 1.0347x over previous
//
#include <hip/hip_runtime.h>
#include <stdint.h>

#define DIM 256
#define NEG_SLOPE 0.01f

#define NBLK 64        // coarse scatter blocks
#define MAXK 1568      // max coarse buckets (N <= 100352)
#define ROWS_PER_BUCKET 64

typedef float    vfloat4 __attribute__((ext_vector_type(4)));
typedef _Float16 vhalf4  __attribute__((ext_vector_type(4)));
typedef unsigned int vuint2 __attribute__((ext_vector_type(2)));

// ---------------- utility kernels ----------------

__global__ __launch_bounds__(256) void zero_i32_kernel(int* __restrict__ p, int n) {
    int i = blockIdx.x * blockDim.x + threadIdx.x;
    int stride = gridDim.x * blockDim.x;
    for (; i < n; i += stride) p[i] = 0;
}

__global__ __launch_bounds__(256) void zero_f32_kernel(float* __restrict__ p, long long n) {
    long long i = (long long)blockIdx.x * blockDim.x + threadIdx.x;
    long long stride = (long long)gridDim.x * blockDim.x;
    for (; i < n; i += stride) p[i] = 0.0f;
}

// ---------------- GEMM: h = x @ W^T + b  (fp32 math, fp16 output) ----------------

#define GBM 128
#define GBN 64
#define GBK 16
#define GLDA 132
#define GLDB 68

__global__ __launch_bounds__(256) void gemm_xwT_kernel(
        const float* __restrict__ x, const float* __restrict__ W,
        const float* __restrict__ bias, _Float16* __restrict__ h, int M) {
    __shared__ float As[GBK][GLDA];
    __shared__ float Bs[GBK][GLDB];

    const int tid  = threadIdx.x;
    const int row0 = blockIdx.x * GBM;
    const int col0 = blockIdx.y * GBN;
    const int ty = tid >> 4;
    const int tx = tid & 15;
    const int lr = tid >> 2;
    const int lk = (tid & 3) * 4;

    float acc[8][4];
#pragma unroll
    for (int i = 0; i < 8; ++i)
#pragma unroll
        for (int j = 0; j < 4; ++j) acc[i][j] = 0.0f;

    for (int kk = 0; kk < DIM; kk += GBK) {
#pragma unroll
        for (int i = 0; i < 2; ++i) {
            int row = row0 + lr + i * 64;
            vfloat4 av = {0.f, 0.f, 0.f, 0.f};
            if (row < M)
                av = __builtin_nontemporal_load((const vfloat4*)(&x[(size_t)row * DIM + kk + lk]));
            As[lk + 0][lr + i * 64] = av.x; As[lk + 1][lr + i * 64] = av.y;
            As[lk + 2][lr + i * 64] = av.z; As[lk + 3][lr + i * 64] = av.w;
        }
        float4 bv = *(const float4*)(&W[(size_t)(col0 + lr) * DIM + kk + lk]);
        Bs[lk + 0][lr] = bv.x; Bs[lk + 1][lr] = bv.y;
        Bs[lk + 2][lr] = bv.z; Bs[lk + 3][lr] = bv.w;
        __syncthreads();

#pragma unroll
        for (int k = 0; k < GBK; ++k) {
            float4 a0 = *(const float4*)(&As[k][ty * 8]);
            float4 a1 = *(const float4*)(&As[k][ty * 8 + 4]);
            float4 b  = *(const float4*)(&Bs[k][tx * 4]);
            float ar[8] = {a0.x, a0.y, a0.z, a0.w, a1.x, a1.y, a1.z, a1.w};
            float br[4] = {b.x, b.y, b.z, b.w};
#pragma unroll
            for (int i = 0; i < 8; ++i)
#pragma unroll
                for (int j = 0; j < 4; ++j)
                    acc[i][j] += ar[i] * br[j];
        }
        __syncthreads();
    }

    const float4 bvec = *(const float4*)(&bias[col0 + tx * 4]);
#pragma unroll
    for (int i = 0; i < 8; ++i) {
        int row = row0 + ty * 8 + i;
        if (row < M) {
            vhalf4 o;
            o.x = (_Float16)(acc[i][0] + bvec.x);
            o.y = (_Float16)(acc[i][1] + bvec.y);
            o.z = (_Float16)(acc[i][2] + bvec.z);
            o.w = (_Float16)(acc[i][3] + bvec.w);
            *(vhalf4*)(&h[(size_t)row * DIM + col0 + tx * 4]) = o;
        }
    }
}

// ---------------- row-level CSR offsets ----------------

__global__ __launch_bounds__(256) void hist_kernel(const int* __restrict__ rows,
                                                   int* __restrict__ cnt, int E) {
    int i = blockIdx.x * blockDim.x + threadIdx.x;
    int stride = gridDim.x * blockDim.x;
    for (; i < E; i += stride)
        atomicAdd(&cnt[__builtin_nontemporal_load(&rows[i])], 1);
}

__device__ inline int wave_incl_scan(int v) {
    const int lane = threadIdx.x & 63;
#pragma unroll
    for (int off = 1; off < 64; off <<= 1) {
        int t = __shfl_up(v, off, 64);
        if (lane >= off) v += t;
    }
    return v;
}

#define SCHUNK 2048   // 256 threads x 8 elements

__global__ __launch_bounds__(256) void chunk_sum_kernel(const int* __restrict__ cnt,
                                                        int* __restrict__ psum, int n) {
    __shared__ int wtot[4];
    const int tid = (int)threadIdx.x;
    const int lane = tid & 63, wid = tid >> 6;
    const int base = blockIdx.x * SCHUNK + tid * 8;
    int s = 0;
#pragma unroll
    for (int i = 0; i < 8; ++i) {
        int idx = base + i;
        if (idx < n) s += cnt[idx];
    }
#pragma unroll
    for (int off = 32; off; off >>= 1) s += __shfl_xor(s, off, 64);
    if (lane == 0) wtot[wid] = s;
    __syncthreads();
    if (tid == 0) psum[blockIdx.x] = wtot[0] + wtot[1] + wtot[2] + wtot[3];
}

__global__ __launch_bounds__(64) void scan_psum_kernel(int* __restrict__ psum, int nchunks) {
    const int lane = (int)threadIdx.x;
    int run = 0;
    for (int b = 0; b < nchunks; b += 64) {
        int i = b + lane;
        int v = (i < nchunks) ? psum[i] : 0;
        int incl = wave_incl_scan(v);
        if (i < nchunks) psum[i] = run + incl - v;
        run += __shfl(incl, 63, 64);
    }
}

__global__ __launch_bounds__(256) void scan_final_kernel(const int* __restrict__ cnt,
        const int* __restrict__ psum, int* __restrict__ offs, int n) {
    __shared__ int wtot[4];
    const int tid = (int)threadIdx.x;
    const int lane = tid & 63, wid = tid >> 6;
    const int base = blockIdx.x * SCHUNK + tid * 8;
    int v[8];
    int ts = 0;
#pragma unroll
    for (int i = 0; i < 8; ++i) {
        int idx = base + i;
        v[i] = (idx < n) ? cnt[idx] : 0;
        ts += v[i];
    }
    int incl = wave_incl_scan(ts);
    if (lane == 63) wtot[wid] = incl;
    __syncthreads();
    int woff = 0;
    for (int w = 0; w < wid; ++w) woff += wtot[w];
    int run = psum[blockIdx.x] + woff + incl - ts;
#pragma unroll
    for (int i = 0; i < 8; ++i) {
        int idx = base + i;
        if (idx < n) offs[idx] = run;
        run += v[i];
    }
}

// ---------------- two-level sort ----------------
// Level 1: coarse bucket = row>>6. Per-(block,bucket) contiguous regions ->
// sequential writes, no cross-XCD line sharing.

__global__ __launch_bounds__(256) void hist2_kernel(const int* __restrict__ rows,
        int* __restrict__ hist2 /*[K][NBLK]*/, int E, int K, int chunk) {
    __shared__ int lh[MAXK];
    const int tid = (int)threadIdx.x;
    const int b = (int)blockIdx.x;
    for (int i = tid; i < K; i += 256) lh[i] = 0;
    __syncthreads();
    const int beg = b * chunk;
    const int end = min(beg + chunk, E);
    for (int i = beg + tid; i < end; i += 256)
        atomicAdd(&lh[__builtin_nontemporal_load(&rows[i]) >> 6], 1);
    __syncthreads();
    for (int i = tid; i < K; i += 256) hist2[i * NBLK + b] = lh[i];
}

// offs2[k][b] = offs[64k] + sum_{b'<b} hist2[k][b']
__global__ __launch_bounds__(256) void scan2_kernel(const int* __restrict__ hist2,
        const int* __restrict__ offs, int* __restrict__ offs2, int K) {
    int k = blockIdx.x * blockDim.x + threadIdx.x;
    if (k >= K) return;
    int run = offs[k * ROWS_PER_BUCKET];
#pragma unroll 4
    for (int b = 0; b < NBLK; ++b) {
        offs2[k * NBLK + b] = run;
        run += hist2[k * NBLK + b];
    }
}

__global__ __launch_bounds__(256) void coarse_scatter_kernel(
        const int* __restrict__ rows, const int* __restrict__ cols,
        const float* __restrict__ vals, const int* __restrict__ offs2,
        vuint2* __restrict__ coarse, int E, int K, int chunk) {
    __shared__ int cur[MAXK];
    const int tid = (int)threadIdx.x;
    const int b = (int)blockIdx.x;
    for (int i = tid; i < K; i += 256) cur[i] = offs2[i * NBLK + b];
    __syncthreads();
    const int beg = b * chunk;
    const int end = min(beg + chunk, E);
    for (int i = beg + tid; i < end; i += 256) {
        int r = __builtin_nontemporal_load(&rows[i]);
        int c = __builtin_nontemporal_load(&cols[i]);
        float v = __builtin_nontemporal_load(&vals[i]);
        int pos = atomicAdd(&cur[r >> 6], 1);
        vuint2 rec;
        rec.x = ((unsigned)(r & 63) << 18) | (unsigned)c;   // row_local | col
        rec.y = __float_as_uint(v);
        coarse[pos] = rec;
    }
}

// Level 2: per-bucket counting sort by row. Random writes confined to a
// ~16KB single-block region -> full line merging in that block's L2.
__global__ __launch_bounds__(256) void fine_sort_kernel(
        const vuint2* __restrict__ coarse, const int* __restrict__ offs,
        vuint2* __restrict__ sorted, int N, int E, int K) {
    __shared__ int cur[ROWS_PER_BUCKET];
    const int tid = (int)threadIdx.x;
    const int k = (int)blockIdx.x;
    const int row0 = k * ROWS_PER_BUCKET;
    if (tid < ROWS_PER_BUCKET) {
        int row = row0 + tid;
        cur[tid] = (row < N) ? offs[row] : E;
    }
    const int beg = offs[row0];
    const int end = (row0 + ROWS_PER_BUCKET < N) ? offs[row0 + ROWS_PER_BUCKET] : E;
    __syncthreads();
    for (int j = beg + tid; j < end; j += 256) {
        vuint2 rec = __builtin_nontemporal_load(&coarse[j]);
        int rl = (int)(rec.x >> 18);
        int pos = atomicAdd(&cur[rl], 1);
        sorted[pos] = rec;
    }
}

// ---------------- aggregation: one wave per node, 4 nodes/block ----------------

__global__ __launch_bounds__(256) void agg_kernel(
        const _Float16* __restrict__ h, const vuint2* __restrict__ sorted,
        const int* __restrict__ offs, float* __restrict__ out, int N, int E) {
    const int node = blockIdx.x * 4 + ((int)threadIdx.x >> 6);
    if (node >= N) return;
    const int lane = (int)threadIdx.x & 63;
    const int beg = offs[node];
    const int end = (node + 1 < N) ? offs[node + 1] : E;

    float4 acc0 = make_float4(0.f, 0.f, 0.f, 0.f);
    float4 acc1 = make_float4(0.f, 0.f, 0.f, 0.f);

    int j = beg;
    for (; j + 7 < end; j += 8) {
        vuint2 cv[8];
        vhalf4 hv[8];
#pragma unroll
        for (int u = 0; u < 8; ++u) cv[u] = __builtin_nontemporal_load(&sorted[j + u]);
#pragma unroll
        for (int u = 0; u < 8; ++u)
            hv[u] = *(const vhalf4*)(&h[(size_t)(cv[u].x & 0x3FFFF) * DIM + lane * 4]);
#pragma unroll
        for (int u = 0; u < 8; ++u) {
            float v = __uint_as_float(cv[u].y);
            float4* a = (u & 1) ? &acc1 : &acc0;
            a->x += v * (float)hv[u].x;
            a->y += v * (float)hv[u].y;
            a->z += v * (float)hv[u].z;
            a->w += v * (float)hv[u].w;
        }
    }
    for (; j < end; ++j) {
        vuint2 cv = __builtin_nontemporal_load(&sorted[j]);
        float v = __uint_as_float(cv.y);
        vhalf4 hv = *(const vhalf4*)(&h[(size_t)(cv.x & 0x3FFFF) * DIM + lane * 4]);
        acc0.x += v * (float)hv.x; acc0.y += v * (float)hv.y;
        acc0.z += v * (float)hv.z; acc0.w += v * (float)hv.w;
    }
    vfloat4 a;
    a.x = acc0.x + acc1.x;
    a.y = acc0.y + acc1.y;
    a.z = acc0.z + acc1.z;
    a.w = acc0.w + acc1.w;
    a.x = (a.x >= 0.f) ? a.x : NEG_SLOPE * a.x;
    a.y = (a.y >= 0.f) ? a.y : NEG_SLOPE * a.y;
    a.z = (a.z >= 0.f) ? a.z : NEG_SLOPE * a.z;
    a.w = (a.w >= 0.f) ? a.w : NEG_SLOPE * a.w;
    __builtin_nontemporal_store(a, (vfloat4*)(&out[(size_t)node * DIM + lane * 4]));
}

// ---------------- fallback: atomic scatter ----------------

__global__ __launch_bounds__(64) void edge_atomic_kernel(
        const int* __restrict__ rows, const int* __restrict__ cols,
        const float* __restrict__ vals, const _Float16* __restrict__ h,
        float* __restrict__ out, int E) {
    const int e = blockIdx.x;
    if (e >= E) return;
    const int lane = threadIdx.x;
    const int r = rows[e];
    const int c = cols[e];
    const float v = vals[e];
    vhalf4 hv = *(const vhalf4*)(&h[(size_t)c * DIM + lane * 4]);
    float* dst = &out[(size_t)r * DIM + lane * 4];
    atomicAdd(dst + 0, v * (float)hv.x);
    atomicAdd(dst + 1, v * (float)hv.y);
    atomicAdd(dst + 2, v * (float)hv.z);
    atomicAdd(dst + 3, v * (float)hv.w);
}

__global__ __launch_bounds__(256) void leaky_kernel(float* __restrict__ p, long long n) {
    long long i = (long long)blockIdx.x * blockDim.x + threadIdx.x;
    long long stride = (long long)gridDim.x * blockDim.x;
    for (; i < n; i += stride) {
        float v = p[i];
        p[i] = (v >= 0.f) ? v : NEG_SLOPE * v;
    }
}

// ---------------- launch ----------------

extern "C" void kernel_launch(void* const* d_in, const int* in_sizes, int n_in,
                              void* d_out, int out_size, void* d_ws, size_t ws_size,
                              hipStream_t stream) {
    const float* x    = (const float*)d_in[0];
    const int*   erow = (const int*)d_in[1];
    const int*   ecol = (const int*)d_in[2];
    const float* eval_ = (const float*)d_in[3];
    const float* Ww   = (const float*)d_in[4];
    const float* Wb   = (const float*)d_in[5];
    float* out = (float*)d_out;

    const int N = in_sizes[0] / DIM;
    const int E = in_sizes[1];
    const int nchunks = (N + SCHUNK - 1) / SCHUNK;
    const int K = (N + ROWS_PER_BUCKET - 1) / ROWS_PER_BUCKET;
    const int chunk = (E + NBLK - 1) / NBLK;

    // workspace layout
    char* p = (char*)d_ws;
    _Float16* h = (_Float16*)p;                 p += (size_t)N * DIM * sizeof(_Float16);
    int* cnt = (int*)p;                         p += (size_t)N * sizeof(int);
    int* offs = (int*)p;                        p += (size_t)N * sizeof(int);
    int* hist2 = (int*)p;                       p += (size_t)K * NBLK * sizeof(int);
    int* offs2 = (int*)p;                       p += (size_t)K * NBLK * sizeof(int);
    int* psum = (int*)p;                        p += (size_t)((nchunks + 63) & ~63) * sizeof(int);
    uintptr_t up = ((uintptr_t)p + 15) & ~(uintptr_t)15;
    vuint2* sorted = (vuint2*)up;
    size_t need_full = (size_t)((char*)sorted - (char*)d_ws) + (size_t)E * sizeof(vuint2);
    size_t need_h = (size_t)N * DIM * sizeof(_Float16);
    // d_out doubles as the coarse-sorted scratch (fully overwritten by agg)
    bool coarse_fits = ((size_t)out_size * sizeof(float)) >= (size_t)E * sizeof(vuint2);

    dim3 ggrid((N + GBM - 1) / GBM, DIM / GBN);

    if (ws_size >= need_full && K <= MAXK && coarse_fits) {
        vuint2* coarse = (vuint2*)d_out;
        // row-level CSR offsets
        zero_i32_kernel<<<256, 256, 0, stream>>>(cnt, N);
        hist_kernel<<<1024, 256, 0, stream>>>(erow, cnt, E);
        chunk_sum_kernel<<<nchunks, 256, 0, stream>>>(cnt, psum, N);
        scan_psum_kernel<<<1, 64, 0, stream>>>(psum, nchunks);
        scan_final_kernel<<<nchunks, 256, 0, stream>>>(cnt, psum, offs, N);
        // two-level sort
        hist2_kernel<<<NBLK, 256, 0, stream>>>(erow, hist2, E, K, chunk);
        scan2_kernel<<<(K + 255) / 256, 256, 0, stream>>>(hist2, offs, offs2, K);
        coarse_scatter_kernel<<<NBLK, 256, 0, stream>>>(erow, ecol, eval_, offs2,
                                                        coarse, E, K, chunk);
        fine_sort_kernel<<<K, 256, 0, stream>>>(coarse, offs, sorted, N, E, K);
        // h = x @ W^T + b (fp16 out)
        gemm_xwT_kernel<<<ggrid, 256, 0, stream>>>(x, Ww, Wb, h, N);
        // aggregation + fused leaky-relu (overwrites coarse scratch)
        agg_kernel<<<(N + 3) / 4, 256, 0, stream>>>(h, sorted, offs, out, N, E);
    } else if (ws_size >= need_h) {
        gemm_xwT_kernel<<<ggrid, 256, 0, stream>>>(x, Ww, Wb, h, N);
        zero_f32_kernel<<<2048, 256, 0, stream>>>(out, (long long)N * DIM);
        edge_atomic_kernel<<<E, 64, 0, stream>>>(erow, ecol, eval_, h, out, E);
        leaky_kernel<<<2048, 256, 0, stream>>>(out, (long long)N * DIM);
    }
}

// Round 7
// 646.177 us; speedup vs baseline: 1.2692x; 1.2266x over previous
//
#include <hip/hip_runtime.h>
#include <stdint.h>

#define DIM 256
#define NEG_SLOPE 0.01f

#define NBLK 256        // coarse scatter blocks
#define MAXK 400        // max coarse buckets (N <= 102400)
#define ROWS_PER_BUCKET 256

typedef float    vfloat4 __attribute__((ext_vector_type(4)));
typedef _Float16 vhalf4  __attribute__((ext_vector_type(4)));
typedef _Float16 half8   __attribute__((ext_vector_type(8)));
typedef float    floatx4 __attribute__((ext_vector_type(4)));
typedef unsigned int vuint2 __attribute__((ext_vector_type(2)));

// ---------------- utility kernels ----------------

__global__ __launch_bounds__(256) void zero_i32_kernel(int* __restrict__ p, int n) {
    int i = blockIdx.x * blockDim.x + threadIdx.x;
    int stride = gridDim.x * blockDim.x;
    for (; i < n; i += stride) p[i] = 0;
}

__global__ __launch_bounds__(256) void zero_f32_kernel(float* __restrict__ p, long long n) {
    long long i = (long long)blockIdx.x * blockDim.x + threadIdx.x;
    long long stride = (long long)gridDim.x * blockDim.x;
    for (; i < n; i += stride) p[i] = 0.0f;
}

// ---------------- GEMM: h = x @ W^T + b  (fp16 MFMA, fp32 accum, fp16 out) ---------
// Tile 128x64 per 256-thread block (4 waves, 2x2). BK=32 (one MFMA K-step).
// A/B frag: row/col = lane&15, k = (lane>>4)*8 + j (8 consecutive f16).
// C/D: col = lane&15, row = (lane>>4)*4 + reg.

#define MBM 128
#define MBN 64
#define MBK 32
#define MLDP 40   // padded LDS row (f16): 80B = 16B-aligned, 2-way bank alias (free)

__global__ __launch_bounds__(256) void gemm_xwT_kernel(
        const float* __restrict__ x, const float* __restrict__ W,
        const float* __restrict__ bias, _Float16* __restrict__ h, int M) {
    __shared__ _Float16 Ax[MBM][MLDP];
    __shared__ _Float16 Bw[MBN][MLDP];

    const int tid  = (int)threadIdx.x;
    const int row0 = blockIdx.x * MBM;
    const int col0 = blockIdx.y * MBN;
    const int wid  = tid >> 6;
    const int lane = tid & 63;
    const int wr = wid >> 1;          // 0..1 : rows wr*64 ..
    const int wc = wid & 1;           // 0..1 : cols wc*32 ..
    const int fr = lane & 15;
    const int fk = (lane >> 4) * 8;

    // staging coords
    const int arow = tid >> 1;              // 0..127
    const int ak   = (tid & 1) * 16;        // 0,16
    const int wrow = tid >> 2;              // 0..63
    const int wk   = (tid & 3) * 8;         // 0,8,16,24

    floatx4 acc[4][2];
#pragma unroll
    for (int m = 0; m < 4; ++m)
#pragma unroll
        for (int n = 0; n < 2; ++n) acc[m][n] = (floatx4){0.f, 0.f, 0.f, 0.f};

    for (int kk = 0; kk < DIM; kk += MBK) {
        // stage A (x): 128 rows x 32 k, fp32 -> fp16
        {
            int grow = row0 + arow;
            const float* src = &x[(size_t)grow * DIM + kk + ak];
            half8 h0, h1;
            if (grow < M) {
                vfloat4 f0 = __builtin_nontemporal_load((const vfloat4*)(src + 0));
                vfloat4 f1 = __builtin_nontemporal_load((const vfloat4*)(src + 4));
                vfloat4 f2 = __builtin_nontemporal_load((const vfloat4*)(src + 8));
                vfloat4 f3 = __builtin_nontemporal_load((const vfloat4*)(src + 12));
                h0 = (half8){(_Float16)f0.x, (_Float16)f0.y, (_Float16)f0.z, (_Float16)f0.w,
                             (_Float16)f1.x, (_Float16)f1.y, (_Float16)f1.z, (_Float16)f1.w};
                h1 = (half8){(_Float16)f2.x, (_Float16)f2.y, (_Float16)f2.z, (_Float16)f2.w,
                             (_Float16)f3.x, (_Float16)f3.y, (_Float16)f3.z, (_Float16)f3.w};
            } else {
                h0 = (half8)(_Float16)0; h1 = (half8)(_Float16)0;
            }
            *(half8*)&Ax[arow][ak]     = h0;
            *(half8*)&Ax[arow][ak + 8] = h1;
        }
        // stage B (W): 64 rows x 32 k
        {
            const float* src = &W[(size_t)(col0 + wrow) * DIM + kk + wk];
            vfloat4 f0 = *(const vfloat4*)(src + 0);
            vfloat4 f1 = *(const vfloat4*)(src + 4);
            half8 hb = (half8){(_Float16)f0.x, (_Float16)f0.y, (_Float16)f0.z, (_Float16)f0.w,
                               (_Float16)f1.x, (_Float16)f1.y, (_Float16)f1.z, (_Float16)f1.w};
            *(half8*)&Bw[wrow][wk] = hb;
        }
        __syncthreads();

        half8 a[4], b[2];
#pragma unroll
        for (int m = 0; m < 4; ++m)
            a[m] = *(const half8*)&Ax[wr * 64 + m * 16 + fr][fk];
#pragma unroll
        for (int n = 0; n < 2; ++n)
            b[n] = *(const half8*)&Bw[wc * 32 + n * 16 + fr][fk];
#pragma unroll
        for (int m = 0; m < 4; ++m)
#pragma unroll
            for (int n = 0; n < 2; ++n)
                acc[m][n] = __builtin_amdgcn_mfma_f32_16x16x32_f16(a[m], b[n], acc[m][n], 0, 0, 0);
        __syncthreads();
    }

#pragma unroll
    for (int m = 0; m < 4; ++m) {
#pragma unroll
        for (int n = 0; n < 2; ++n) {
            int col = col0 + wc * 32 + n * 16 + fr;
            float bv = bias[col];
#pragma unroll
            for (int j = 0; j < 4; ++j) {
                int row = row0 + wr * 64 + m * 16 + (lane >> 4) * 4 + j;
                if (row < M)
                    h[(size_t)row * DIM + col] = (_Float16)(acc[m][n][j] + bv);
            }
        }
    }
}

// ---------------- row-level CSR offsets ----------------

__global__ __launch_bounds__(256) void hist_kernel(const int* __restrict__ rows,
                                                   int* __restrict__ cnt, int E) {
    int i = blockIdx.x * blockDim.x + threadIdx.x;
    int stride = gridDim.x * blockDim.x;
    for (; i < E; i += stride)
        atomicAdd(&cnt[__builtin_nontemporal_load(&rows[i])], 1);
}

__device__ inline int wave_incl_scan(int v) {
    const int lane = threadIdx.x & 63;
#pragma unroll
    for (int off = 1; off < 64; off <<= 1) {
        int t = __shfl_up(v, off, 64);
        if (lane >= off) v += t;
    }
    return v;
}

#define SCHUNK 2048   // 256 threads x 8 elements

__global__ __launch_bounds__(256) void chunk_sum_kernel(const int* __restrict__ cnt,
                                                        int* __restrict__ psum, int n) {
    __shared__ int wtot[4];
    const int tid = (int)threadIdx.x;
    const int lane = tid & 63, wid = tid >> 6;
    const int base = blockIdx.x * SCHUNK + tid * 8;
    int s = 0;
#pragma unroll
    for (int i = 0; i < 8; ++i) {
        int idx = base + i;
        if (idx < n) s += cnt[idx];
    }
#pragma unroll
    for (int off = 32; off; off >>= 1) s += __shfl_xor(s, off, 64);
    if (lane == 0) wtot[wid] = s;
    __syncthreads();
    if (tid == 0) psum[blockIdx.x] = wtot[0] + wtot[1] + wtot[2] + wtot[3];
}

__global__ __launch_bounds__(64) void scan_psum_kernel(int* __restrict__ psum, int nchunks) {
    const int lane = (int)threadIdx.x;
    int run = 0;
    for (int b = 0; b < nchunks; b += 64) {
        int i = b + lane;
        int v = (i < nchunks) ? psum[i] : 0;
        int incl = wave_incl_scan(v);
        if (i < nchunks) psum[i] = run + incl - v;
        run += __shfl(incl, 63, 64);
    }
}

__global__ __launch_bounds__(256) void scan_final_kernel(const int* __restrict__ cnt,
        const int* __restrict__ psum, int* __restrict__ offs, int n) {
    __shared__ int wtot[4];
    const int tid = (int)threadIdx.x;
    const int lane = tid & 63, wid = tid >> 6;
    const int base = blockIdx.x * SCHUNK + tid * 8;
    int v[8];
    int ts = 0;
#pragma unroll
    for (int i = 0; i < 8; ++i) {
        int idx = base + i;
        v[i] = (idx < n) ? cnt[idx] : 0;
        ts += v[i];
    }
    int incl = wave_incl_scan(ts);
    if (lane == 63) wtot[wid] = incl;
    __syncthreads();
    int woff = 0;
    for (int w = 0; w < wid; ++w) woff += wtot[w];
    int run = psum[blockIdx.x] + woff + incl - ts;
#pragma unroll
    for (int i = 0; i < 8; ++i) {
        int idx = base + i;
        if (idx < n) offs[idx] = run;
        run += v[i];
    }
}

// ---------------- two-level sort ----------------
// Level 1: coarse bucket = row>>8 (256 rows). Per-(block,bucket) contiguous regions.

__global__ __launch_bounds__(256) void hist2_kernel(const int* __restrict__ rows,
        int* __restrict__ hist2 /*[K][NBLK]*/, int E, int K, int chunk) {
    __shared__ int lh[MAXK];
    const int tid = (int)threadIdx.x;
    const int b = (int)blockIdx.x;
    for (int i = tid; i < K; i += 256) lh[i] = 0;
    __syncthreads();
    const int beg = b * chunk;
    const int end = min(beg + chunk, E);
    for (int i = beg + tid; i < end; i += 256)
        atomicAdd(&lh[__builtin_nontemporal_load(&rows[i]) >> 8], 1);
    __syncthreads();
    for (int i = tid; i < K; i += 256) hist2[i * NBLK + b] = lh[i];
}

// offs2[k][b] = offs[256k] + sum_{b'<b} hist2[k][b']
__global__ __launch_bounds__(256) void scan2_kernel(const int* __restrict__ hist2,
        const int* __restrict__ offs, int* __restrict__ offs2, int K) {
    int k = blockIdx.x * blockDim.x + threadIdx.x;
    if (k >= K) return;
    int run = offs[k * ROWS_PER_BUCKET];
#pragma unroll 4
    for (int b = 0; b < NBLK; ++b) {
        offs2[k * NBLK + b] = run;
        run += hist2[k * NBLK + b];
    }
}

__global__ __launch_bounds__(256) void coarse_scatter_kernel(
        const int* __restrict__ rows, const int* __restrict__ cols,
        const float* __restrict__ vals, const int* __restrict__ offs2,
        vuint2* __restrict__ coarse, int E, int K, int chunk) {
    __shared__ int cur[MAXK];
    const int tid = (int)threadIdx.x;
    const int b = (int)blockIdx.x;
    for (int i = tid; i < K; i += 256) cur[i] = offs2[i * NBLK + b];
    __syncthreads();
    const int beg = b * chunk;
    const int end = min(beg + chunk, E);
    for (int i = beg + tid; i < end; i += 256) {
        int r = __builtin_nontemporal_load(&rows[i]);
        int c = __builtin_nontemporal_load(&cols[i]);
        float v = __builtin_nontemporal_load(&vals[i]);
        int pos = atomicAdd(&cur[r >> 8], 1);
        vuint2 rec;
        rec.x = ((unsigned)(r & 255) << 18) | (unsigned)c;   // row_local | col (18b)
        rec.y = __float_as_uint(v);
        coarse[pos] = rec;
    }
}

// Level 2: per-bucket counting sort by row. Random writes confined to ~64KB
// single-block region -> line merging in that block's L2.
__global__ __launch_bounds__(256) void fine_sort_kernel(
        const vuint2* __restrict__ coarse, const int* __restrict__ offs,
        vuint2* __restrict__ sorted, int N, int E) {
    __shared__ int cur[ROWS_PER_BUCKET];
    const int tid = (int)threadIdx.x;
    const int k = (int)blockIdx.x;
    const int row0 = k * ROWS_PER_BUCKET;
    {
        int row = row0 + tid;
        cur[tid] = (row < N) ? offs[row] : E;
    }
    const int beg = offs[row0];
    const int end = (row0 + ROWS_PER_BUCKET < N) ? offs[row0 + ROWS_PER_BUCKET] : E;
    __syncthreads();
    for (int j = beg + tid; j < end; j += 256) {
        vuint2 rec = __builtin_nontemporal_load(&coarse[j]);
        int rl = (int)(rec.x >> 18);
        int pos = atomicAdd(&cur[rl], 1);
        sorted[pos] = rec;
    }
}

// ---------------- aggregation: one wave per node, 4 nodes/block ----------------

__global__ __launch_bounds__(256) void agg_kernel(
        const _Float16* __restrict__ h, const vuint2* __restrict__ sorted,
        const int* __restrict__ offs, float* __restrict__ out, int N, int E) {
    const int node = blockIdx.x * 4 + ((int)threadIdx.x >> 6);
    if (node >= N) return;
    const int lane = (int)threadIdx.x & 63;
    const int beg = offs[node];
    const int end = (node + 1 < N) ? offs[node + 1] : E;

    float4 acc0 = make_float4(0.f, 0.f, 0.f, 0.f);
    float4 acc1 = make_float4(0.f, 0.f, 0.f, 0.f);

    int j = beg;
    for (; j + 7 < end; j += 8) {
        vuint2 cv[8];
        vhalf4 hv[8];
#pragma unroll
        for (int u = 0; u < 8; ++u) cv[u] = __builtin_nontemporal_load(&sorted[j + u]);
#pragma unroll
        for (int u = 0; u < 8; ++u)
            hv[u] = *(const vhalf4*)(&h[(size_t)(cv[u].x & 0x3FFFF) * DIM + lane * 4]);
#pragma unroll
        for (int u = 0; u < 8; ++u) {
            float v = __uint_as_float(cv[u].y);
            float4* a = (u & 1) ? &acc1 : &acc0;
            a->x += v * (float)hv[u].x;
            a->y += v * (float)hv[u].y;
            a->z += v * (float)hv[u].z;
            a->w += v * (float)hv[u].w;
        }
    }
    for (; j < end; ++j) {
        vuint2 cv = __builtin_nontemporal_load(&sorted[j]);
        float v = __uint_as_float(cv.y);
        vhalf4 hv = *(const vhalf4*)(&h[(size_t)(cv.x & 0x3FFFF) * DIM + lane * 4]);
        acc0.x += v * (float)hv.x; acc0.y += v * (float)hv.y;
        acc0.z += v * (float)hv.z; acc0.w += v * (float)hv.w;
    }
    vfloat4 a;
    a.x = acc0.x + acc1.x;
    a.y = acc0.y + acc1.y;
    a.z = acc0.z + acc1.z;
    a.w = acc0.w + acc1.w;
    a.x = (a.x >= 0.f) ? a.x : NEG_SLOPE * a.x;
    a.y = (a.y >= 0.f) ? a.y : NEG_SLOPE * a.y;
    a.z = (a.z >= 0.f) ? a.z : NEG_SLOPE * a.z;
    a.w = (a.w >= 0.f) ? a.w : NEG_SLOPE * a.w;
    __builtin_nontemporal_store(a, (vfloat4*)(&out[(size_t)node * DIM + lane * 4]));
}

// ---------------- fallback: atomic scatter ----------------

__global__ __launch_bounds__(64) void edge_atomic_kernel(
        const int* __restrict__ rows, const int* __restrict__ cols,
        const float* __restrict__ vals, const _Float16* __restrict__ h,
        float* __restrict__ out, int E) {
    const int e = blockIdx.x;
    if (e >= E) return;
    const int lane = threadIdx.x;
    const int r = rows[e];
    const int c = cols[e];
    const float v = vals[e];
    vhalf4 hv = *(const vhalf4*)(&h[(size_t)c * DIM + lane * 4]);
    float* dst = &out[(size_t)r * DIM + lane * 4];
    atomicAdd(dst + 0, v * (float)hv.x);
    atomicAdd(dst + 1, v * (float)hv.y);
    atomicAdd(dst + 2, v * (float)hv.z);
    atomicAdd(dst + 3, v * (float)hv.w);
}

__global__ __launch_bounds__(256) void leaky_kernel(float* __restrict__ p, long long n) {
    long long i = (long long)blockIdx.x * blockDim.x + threadIdx.x;
    long long stride = (long long)gridDim.x * blockDim.x;
    for (; i < n; i += stride) {
        float v = p[i];
        p[i] = (v >= 0.f) ? v : NEG_SLOPE * v;
    }
}

// ---------------- launch ----------------

extern "C" void kernel_launch(void* const* d_in, const int* in_sizes, int n_in,
                              void* d_out, int out_size, void* d_ws, size_t ws_size,
                              hipStream_t stream) {
    const float* x    = (const float*)d_in[0];
    const int*   erow = (const int*)d_in[1];
    const int*   ecol = (const int*)d_in[2];
    const float* eval_ = (const float*)d_in[3];
    const float* Ww   = (const float*)d_in[4];
    const float* Wb   = (const float*)d_in[5];
    float* out = (float*)d_out;

    const int N = in_sizes[0] / DIM;
    const int E = in_sizes[1];
    const int nchunks = (N + SCHUNK - 1) / SCHUNK;
    const int K = (N + ROWS_PER_BUCKET - 1) / ROWS_PER_BUCKET;
    const int chunk = (E + NBLK - 1) / NBLK;

    // workspace layout
    char* p = (char*)d_ws;
    _Float16* h = (_Float16*)p;                 p += (size_t)N * DIM * sizeof(_Float16);
    int* cnt = (int*)p;                         p += (size_t)N * sizeof(int);
    int* offs = (int*)p;                        p += (size_t)N * sizeof(int);
    int* hist2 = (int*)p;                       p += (size_t)K * NBLK * sizeof(int);
    int* offs2 = (int*)p;                       p += (size_t)K * NBLK * sizeof(int);
    int* psum = (int*)p;                        p += (size_t)((nchunks + 63) & ~63) * sizeof(int);
    uintptr_t up = ((uintptr_t)p + 15) & ~(uintptr_t)15;
    vuint2* sorted = (vuint2*)up;
    size_t need_full = (size_t)((char*)sorted - (char*)d_ws) + (size_t)E * sizeof(vuint2);
    size_t need_h = (size_t)N * DIM * sizeof(_Float16);
    bool coarse_fits = ((size_t)out_size * sizeof(float)) >= (size_t)E * sizeof(vuint2);

    dim3 ggrid((N + MBM - 1) / MBM, DIM / MBN);

    if (ws_size >= need_full && K <= MAXK && coarse_fits && N <= (1 << 18)) {
        vuint2* coarse = (vuint2*)d_out;
        // row-level CSR offsets
        zero_i32_kernel<<<256, 256, 0, stream>>>(cnt, N);
        hist_kernel<<<1024, 256, 0, stream>>>(erow, cnt, E);
        chunk_sum_kernel<<<nchunks, 256, 0, stream>>>(cnt, psum, N);
        scan_psum_kernel<<<1, 64, 0, stream>>>(psum, nchunks);
        scan_final_kernel<<<nchunks, 256, 0, stream>>>(cnt, psum, offs, N);
        // two-level sort
        hist2_kernel<<<NBLK, 256, 0, stream>>>(erow, hist2, E, K, chunk);
        scan2_kernel<<<(K + 255) / 256, 256, 0, stream>>>(hist2, offs, offs2, K);
        coarse_scatter_kernel<<<NBLK, 256, 0, stream>>>(erow, ecol, eval_, offs2,
                                                        coarse, E, K, chunk);
        fine_sort_kernel<<<K, 256, 0, stream>>>(coarse, offs, sorted, N, E);
        // h = x @ W^T + b (fp16 MFMA)
        gemm_xwT_kernel<<<ggrid, 256, 0, stream>>>(x, Ww, Wb, h, N);
        // aggregation + fused leaky-relu (overwrites coarse scratch)
        agg_kernel<<<(N + 3) / 4, 256, 0, stream>>>(h, sorted, offs, out, N, E);
    } else if (ws_size >= need_h) {
        gemm_xwT_kernel<<<ggrid, 256, 0, stream>>>(x, Ww, Wb, h, N);
        zero_f32_kernel<<<2048, 256, 0, stream>>>(out, (long long)N * DIM);
        edge_atomic_kernel<<<E, 64, 0, stream>>>(erow, ecol, eval_, h, out, E);
        leaky_kernel<<<2048, 256, 0, stream>>>(out, (long long)N * DIM);
    }
}

// Round 8
// 498.207 us; speedup vs baseline: 1.6462x; 1.2970x over previous
//
#include <hip/hip_runtime.h>
#include <stdint.h>

#define DIM 256
#define NEG_SLOPE 0.01f

#define NBLK 512            // coarse scatter blocks (2 per CU)
#define MAXK 400            // max coarse buckets (N <= 102400)
#define ROWS_PER_BUCKET 256

typedef float    vfloat4 __attribute__((ext_vector_type(4)));
typedef _Float16 vhalf4  __attribute__((ext_vector_type(4)));
typedef _Float16 half8   __attribute__((ext_vector_type(8)));
typedef float    floatx4 __attribute__((ext_vector_type(4)));
typedef unsigned int vuint2 __attribute__((ext_vector_type(2)));

// ---------------- GEMM: h = x @ W^T + b  (fp16 MFMA, fp32 accum, fp16 out) ---------

#define MBM 128
#define MBN 64
#define MBK 32
#define MLDP 40

__global__ __launch_bounds__(256) void gemm_xwT_kernel(
        const float* __restrict__ x, const float* __restrict__ W,
        const float* __restrict__ bias, _Float16* __restrict__ h, int M) {
    __shared__ _Float16 Ax[MBM][MLDP];
    __shared__ _Float16 Bw[MBN][MLDP];

    const int tid  = (int)threadIdx.x;
    const int row0 = blockIdx.x * MBM;
    const int col0 = blockIdx.y * MBN;
    const int wid  = tid >> 6;
    const int lane = tid & 63;
    const int wr = wid >> 1;
    const int wc = wid & 1;
    const int fr = lane & 15;
    const int fk = (lane >> 4) * 8;

    const int arow = tid >> 1;
    const int ak   = (tid & 1) * 16;
    const int wrow = tid >> 2;
    const int wk   = (tid & 3) * 8;

    floatx4 acc[4][2];
#pragma unroll
    for (int m = 0; m < 4; ++m)
#pragma unroll
        for (int n = 0; n < 2; ++n) acc[m][n] = (floatx4){0.f, 0.f, 0.f, 0.f};

    for (int kk = 0; kk < DIM; kk += MBK) {
        {
            int grow = row0 + arow;
            const float* src = &x[(size_t)grow * DIM + kk + ak];
            half8 h0, h1;
            if (grow < M) {
                vfloat4 f0 = __builtin_nontemporal_load((const vfloat4*)(src + 0));
                vfloat4 f1 = __builtin_nontemporal_load((const vfloat4*)(src + 4));
                vfloat4 f2 = __builtin_nontemporal_load((const vfloat4*)(src + 8));
                vfloat4 f3 = __builtin_nontemporal_load((const vfloat4*)(src + 12));
                h0 = (half8){(_Float16)f0.x, (_Float16)f0.y, (_Float16)f0.z, (_Float16)f0.w,
                             (_Float16)f1.x, (_Float16)f1.y, (_Float16)f1.z, (_Float16)f1.w};
                h1 = (half8){(_Float16)f2.x, (_Float16)f2.y, (_Float16)f2.z, (_Float16)f2.w,
                             (_Float16)f3.x, (_Float16)f3.y, (_Float16)f3.z, (_Float16)f3.w};
            } else {
                h0 = (half8)(_Float16)0; h1 = (half8)(_Float16)0;
            }
            *(half8*)&Ax[arow][ak]     = h0;
            *(half8*)&Ax[arow][ak + 8] = h1;
        }
        {
            const float* src = &W[(size_t)(col0 + wrow) * DIM + kk + wk];
            vfloat4 f0 = *(const vfloat4*)(src + 0);
            vfloat4 f1 = *(const vfloat4*)(src + 4);
            half8 hb = (half8){(_Float16)f0.x, (_Float16)f0.y, (_Float16)f0.z, (_Float16)f0.w,
                               (_Float16)f1.x, (_Float16)f1.y, (_Float16)f1.z, (_Float16)f1.w};
            *(half8*)&Bw[wrow][wk] = hb;
        }
        __syncthreads();

        half8 a[4], b[2];
#pragma unroll
        for (int m = 0; m < 4; ++m)
            a[m] = *(const half8*)&Ax[wr * 64 + m * 16 + fr][fk];
#pragma unroll
        for (int n = 0; n < 2; ++n)
            b[n] = *(const half8*)&Bw[wc * 32 + n * 16 + fr][fk];
#pragma unroll
        for (int m = 0; m < 4; ++m)
#pragma unroll
            for (int n = 0; n < 2; ++n)
                acc[m][n] = __builtin_amdgcn_mfma_f32_16x16x32_f16(a[m], b[n], acc[m][n], 0, 0, 0);
        __syncthreads();
    }

#pragma unroll
    for (int m = 0; m < 4; ++m) {
#pragma unroll
        for (int n = 0; n < 2; ++n) {
            int col = col0 + wc * 32 + n * 16 + fr;
            float bv = bias[col];
#pragma unroll
            for (int j = 0; j < 4; ++j) {
                int row = row0 + wr * 64 + m * 16 + (lane >> 4) * 4 + j;
                if (row < M)
                    h[(size_t)row * DIM + col] = (_Float16)(acc[m][n][j] + bv);
            }
        }
    }
}

// ---------------- bucket-level histogram / scans ----------------

__device__ inline int wave_incl_scan(int v) {
    const int lane = threadIdx.x & 63;
#pragma unroll
    for (int off = 1; off < 64; off <<= 1) {
        int t = __shfl_up(v, off, 64);
        if (lane >= off) v += t;
    }
    return v;
}

// per-chunk bucket histogram: hist2[k][b]
__global__ __launch_bounds__(256) void hist2_kernel(const int* __restrict__ rows,
        int* __restrict__ hist2, int E, int K, int chunk) {
    __shared__ int lh[MAXK];
    const int tid = (int)threadIdx.x;
    const int b = (int)blockIdx.x;
    for (int i = tid; i < K; i += 256) lh[i] = 0;
    __syncthreads();
    const int beg = b * chunk;
    const int end = min(beg + chunk, E);
    for (int i = beg + tid; i < end; i += 256)
        atomicAdd(&lh[__builtin_nontemporal_load(&rows[i]) >> 8], 1);
    __syncthreads();
    for (int i = tid; i < K; i += 256) hist2[i * NBLK + b] = lh[i];
}

// scanA: one wave per bucket k; exclusive prefix over b (in place), total[k] out.
__global__ __launch_bounds__(64) void scanA_kernel(int* __restrict__ hist2,
        int* __restrict__ total, int K) {
    const int k = (int)blockIdx.x;
    const int lane = (int)threadIdx.x;
    int* row = &hist2[k * NBLK];
    int v[8];
    int s = 0;
#pragma unroll
    for (int i = 0; i < 8; ++i) { v[i] = row[lane * 8 + i]; s += v[i]; }
    int incl = wave_incl_scan(s);
    int run = incl - s;   // exclusive base for this lane's segment
#pragma unroll
    for (int i = 0; i < 8; ++i) { row[lane * 8 + i] = run; run += v[i]; }
    if (lane == 63) total[k] = incl;
}

// scanB: single wave exclusive scan of bucket totals -> bbase
__global__ __launch_bounds__(64) void scanB_kernel(const int* __restrict__ total,
        int* __restrict__ bbase, int K) {
    const int lane = (int)threadIdx.x;
    int run = 0;
    for (int b = 0; b < K; b += 64) {
        int i = b + lane;
        int v = (i < K) ? total[i] : 0;
        int incl = wave_incl_scan(v);
        if (i < K) bbase[i] = run + incl - v;
        run += __shfl(incl, 63, 64);
    }
}

// ---------------- coarse scatter: per-(block,bucket) contiguous regions ----------------

__global__ __launch_bounds__(256) void coarse_scatter_kernel(
        const int* __restrict__ rows, const int* __restrict__ cols,
        const float* __restrict__ vals, const int* __restrict__ hist2,
        const int* __restrict__ bbase, vuint2* __restrict__ coarse,
        int E, int K, int chunk) {
    __shared__ int cur[MAXK];
    const int tid = (int)threadIdx.x;
    const int b = (int)blockIdx.x;
    for (int i = tid; i < K; i += 256) cur[i] = bbase[i] + hist2[i * NBLK + b];
    __syncthreads();
    const int beg = b * chunk;
    const int end = min(beg + chunk, E);
    for (int i = beg + tid; i < end; i += 256) {
        int r = __builtin_nontemporal_load(&rows[i]);
        int c = __builtin_nontemporal_load(&cols[i]);
        float v = __builtin_nontemporal_load(&vals[i]);
        int pos = atomicAdd(&cur[r >> 8], 1);
        vuint2 rec;
        rec.x = ((unsigned)(r & 255) << 18) | (unsigned)c;   // row_local | col(18b)
        rec.y = __float_as_uint(v);
        coarse[pos] = rec;
    }
}

// ---------------- fine sort: per-bucket counting sort; also emits offs[] ----------------

__global__ __launch_bounds__(256) void fine_sort_kernel(
        const vuint2* __restrict__ coarse, const int* __restrict__ bbase,
        vuint2* __restrict__ sorted, int* __restrict__ offs,
        int N, int E, int K) {
    __shared__ int lh[ROWS_PER_BUCKET];
    __shared__ int wtot[4];
    const int tid = (int)threadIdx.x;
    const int lane = tid & 63, wid = tid >> 6;
    const int k = (int)blockIdx.x;
    const int row0 = k * ROWS_PER_BUCKET;
    const int beg = bbase[k];
    const int end = (k + 1 < K) ? bbase[k + 1] : E;

    lh[tid] = 0;
    __syncthreads();
    // pass 1: row histogram of this bucket
    for (int j = beg + tid; j < end; j += 256)
        atomicAdd(&lh[coarse[j].x >> 18], 1);
    __syncthreads();
    // block scan (256 values)
    int v = lh[tid];
    int incl = wave_incl_scan(v);
    if (lane == 63) wtot[wid] = incl;
    __syncthreads();
    int woff = 0;
    for (int w = 0; w < wid; ++w) woff += wtot[w];
    int excl = woff + incl - v;
    lh[tid] = beg + excl;       // becomes the scatter cursor
    int row = row0 + tid;
    if (row < N) offs[row] = beg + excl;
    __syncthreads();
    // pass 2: scatter into row-sorted order
    for (int j = beg + tid; j < end; j += 256) {
        vuint2 rec = __builtin_nontemporal_load(&coarse[j]);
        int pos = atomicAdd(&lh[rec.x >> 18], 1);
        sorted[pos] = rec;
    }
}

// ---------------- aggregation: one wave per node, 4 nodes/block ----------------

__global__ __launch_bounds__(256) void agg_kernel(
        const _Float16* __restrict__ h, const vuint2* __restrict__ sorted,
        const int* __restrict__ offs, float* __restrict__ out, int N, int E) {
    const int node = blockIdx.x * 4 + ((int)threadIdx.x >> 6);
    if (node >= N) return;
    const int lane = (int)threadIdx.x & 63;
    const int beg = offs[node];
    const int end = (node + 1 < N) ? offs[node + 1] : E;

    float4 acc0 = make_float4(0.f, 0.f, 0.f, 0.f);
    float4 acc1 = make_float4(0.f, 0.f, 0.f, 0.f);

    int j = beg;
    for (; j + 7 < end; j += 8) {
        vuint2 cv[8];
        vhalf4 hv[8];
#pragma unroll
        for (int u = 0; u < 8; ++u) cv[u] = __builtin_nontemporal_load(&sorted[j + u]);
#pragma unroll
        for (int u = 0; u < 8; ++u)
            hv[u] = *(const vhalf4*)(&h[(size_t)(cv[u].x & 0x3FFFF) * DIM + lane * 4]);
#pragma unroll
        for (int u = 0; u < 8; ++u) {
            float v = __uint_as_float(cv[u].y);
            float4* a = (u & 1) ? &acc1 : &acc0;
            a->x += v * (float)hv[u].x;
            a->y += v * (float)hv[u].y;
            a->z += v * (float)hv[u].z;
            a->w += v * (float)hv[u].w;
        }
    }
    for (; j < end; ++j) {
        vuint2 cv = __builtin_nontemporal_load(&sorted[j]);
        float v = __uint_as_float(cv.y);
        vhalf4 hv = *(const vhalf4*)(&h[(size_t)(cv.x & 0x3FFFF) * DIM + lane * 4]);
        acc0.x += v * (float)hv.x; acc0.y += v * (float)hv.y;
        acc0.z += v * (float)hv.z; acc0.w += v * (float)hv.w;
    }
    vfloat4 a;
    a.x = acc0.x + acc1.x;
    a.y = acc0.y + acc1.y;
    a.z = acc0.z + acc1.z;
    a.w = acc0.w + acc1.w;
    a.x = (a.x >= 0.f) ? a.x : NEG_SLOPE * a.x;
    a.y = (a.y >= 0.f) ? a.y : NEG_SLOPE * a.y;
    a.z = (a.z >= 0.f) ? a.z : NEG_SLOPE * a.z;
    a.w = (a.w >= 0.f) ? a.w : NEG_SLOPE * a.w;
    __builtin_nontemporal_store(a, (vfloat4*)(&out[(size_t)node * DIM + lane * 4]));
}

// ---------------- fallback: atomic scatter ----------------

__global__ __launch_bounds__(256) void zero_f32_kernel(float* __restrict__ p, long long n) {
    long long i = (long long)blockIdx.x * blockDim.x + threadIdx.x;
    long long stride = (long long)gridDim.x * blockDim.x;
    for (; i < n; i += stride) p[i] = 0.0f;
}

__global__ __launch_bounds__(64) void edge_atomic_kernel(
        const int* __restrict__ rows, const int* __restrict__ cols,
        const float* __restrict__ vals, const _Float16* __restrict__ h,
        float* __restrict__ out, int E) {
    const int e = blockIdx.x;
    if (e >= E) return;
    const int lane = threadIdx.x;
    const int r = rows[e];
    const int c = cols[e];
    const float v = vals[e];
    vhalf4 hv = *(const vhalf4*)(&h[(size_t)c * DIM + lane * 4]);
    float* dst = &out[(size_t)r * DIM + lane * 4];
    atomicAdd(dst + 0, v * (float)hv.x);
    atomicAdd(dst + 1, v * (float)hv.y);
    atomicAdd(dst + 2, v * (float)hv.z);
    atomicAdd(dst + 3, v * (float)hv.w);
}

__global__ __launch_bounds__(256) void leaky_kernel(float* __restrict__ p, long long n) {
    long long i = (long long)blockIdx.x * blockDim.x + threadIdx.x;
    long long stride = (long long)gridDim.x * blockDim.x;
    for (; i < n; i += stride) {
        float v = p[i];
        p[i] = (v >= 0.f) ? v : NEG_SLOPE * v;
    }
}

// ---------------- launch ----------------

extern "C" void kernel_launch(void* const* d_in, const int* in_sizes, int n_in,
                              void* d_out, int out_size, void* d_ws, size_t ws_size,
                              hipStream_t stream) {
    const float* x    = (const float*)d_in[0];
    const int*   erow = (const int*)d_in[1];
    const int*   ecol = (const int*)d_in[2];
    const float* eval_ = (const float*)d_in[3];
    const float* Ww   = (const float*)d_in[4];
    const float* Wb   = (const float*)d_in[5];
    float* out = (float*)d_out;

    const int N = in_sizes[0] / DIM;
    const int E = in_sizes[1];
    const int K = (N + ROWS_PER_BUCKET - 1) / ROWS_PER_BUCKET;
    const int chunk = (E + NBLK - 1) / NBLK;

    // workspace layout
    char* p = (char*)d_ws;
    _Float16* h = (_Float16*)p;                 p += (size_t)N * DIM * sizeof(_Float16);
    int* hist2 = (int*)p;                       p += (size_t)K * NBLK * sizeof(int);
    int* total = (int*)p;                       p += (size_t)((K + 63) & ~63) * sizeof(int);
    int* bbase = (int*)p;                       p += (size_t)((K + 63) & ~63) * sizeof(int);
    int* offs = (int*)p;                        p += (size_t)N * sizeof(int);
    uintptr_t up = ((uintptr_t)p + 15) & ~(uintptr_t)15;
    vuint2* sorted = (vuint2*)up;
    size_t need_full = (size_t)((char*)sorted - (char*)d_ws) + (size_t)E * sizeof(vuint2);
    size_t need_h = (size_t)N * DIM * sizeof(_Float16);
    bool coarse_fits = ((size_t)out_size * sizeof(float)) >= (size_t)E * sizeof(vuint2);

    dim3 ggrid((N + MBM - 1) / MBM, DIM / MBN);

    if (ws_size >= need_full && K <= MAXK && coarse_fits && N <= (1 << 18)) {
        vuint2* coarse = (vuint2*)d_out;
        hist2_kernel<<<NBLK, 256, 0, stream>>>(erow, hist2, E, K, chunk);
        scanA_kernel<<<K, 64, 0, stream>>>(hist2, total, K);
        scanB_kernel<<<1, 64, 0, stream>>>(total, bbase, K);
        coarse_scatter_kernel<<<NBLK, 256, 0, stream>>>(erow, ecol, eval_, hist2,
                                                        bbase, coarse, E, K, chunk);
        fine_sort_kernel<<<K, 256, 0, stream>>>(coarse, bbase, sorted, offs, N, E, K);
        gemm_xwT_kernel<<<ggrid, 256, 0, stream>>>(x, Ww, Wb, h, N);
        agg_kernel<<<(N + 3) / 4, 256, 0, stream>>>(h, sorted, offs, out, N, E);
    } else if (ws_size >= need_h) {
        gemm_xwT_kernel<<<ggrid, 256, 0, stream>>>(x, Ww, Wb, h, N);
        zero_f32_kernel<<<2048, 256, 0, stream>>>(out, (long long)N * DIM);
        edge_atomic_kernel<<<E, 64, 0, stream>>>(erow, ecol, eval_, h, out, E);
        leaky_kernel<<<2048, 256, 0, stream>>>(out, (long long)N * DIM);
    }
}